// Round 6
// baseline (318.527 us; speedup 1.0000x reference)
//
#include <hip/hip_runtime.h>
#include <stdint.h>
#include <stddef.h>

// MMD loss, fused: gram = X·X^T (bf16 MFMA) + 5-kernel RBF epilogue + signed mean.
// N=8192 rows (4096 src + 4096 tgt), D=256.
//
// Round-6 structure: NO LDS; Xbt pre-transposed to MFMA fragment order
// (1KB/wave coalesced fragment loads). NEW vs round 5:
//  (a) per-block results go to 256 DISTINCT partial slots (atomicAdd) instead
//      of one shared f64 address — round 4/5 evidence: duration insensitive
//      to coalescing AND locality, consistent with a device-global serialized
//      RMW retire chain (2080 x ~85cyc ~= 75us).
//  (b) 1-wave workgroups (64 thr): one 64x64 quadrant per block, 8320 blocks.
//      No barriers/LDS; 136 regs/wave -> 12 resident waves/CU (was ~7).
//
// Fragment layout: elem(r,k) at (r>>4)*4096 + (k>>3)*128 + (r&15)*8 + (k&7)
// -> lane(lo,hi) fragment base byte = rowgroup*8192 + (kc*4+hi)*256 + lo*16.
//
// ws layout:
//   [0]     int    cnt_colsum
//   [4]     int    cnt_gram
//   [8]     float  coef            (-log2(e) / (16*bandwidth))
//   [16]    double colsum[256]     -> [16, 2064)
//   [2080]  double partial[256]    -> [2080, 4128)
//   [8192]  float  sq[8192]        -> [8192, 40960)
//   [40960] ushort Xbt[8192*256]   (bf16, fragment-transposed)

#define N_TOT 8192
#define D_DIM 256
#define BS    4096
#define NB    64      // 128-row tiles per dim; 2080 upper-tri tiles
#define NQUAD 8320    // 2080 tiles * 4 quadrants (% 8 == 0)

typedef float  f32x4  __attribute__((ext_vector_type(4)));
typedef short  bf16x8 __attribute__((ext_vector_type(8)));

__device__ __forceinline__ unsigned short f2bf(float f) {
  unsigned u = __float_as_uint(f);
  u += 0x7fffu + ((u >> 16) & 1u);   // RNE; inputs are finite
  return (unsigned short)(u >> 16);
}
__device__ __forceinline__ float bf2f(unsigned short s) {
  return __uint_as_float(((unsigned)s) << 16);
}

// ---------------- prep: f32 -> bf16 fragment-transposed copy + row sq-norms ----------------
__global__ void prep_kernel(const float* __restrict__ src, const float* __restrict__ tgt,
                            unsigned short* __restrict__ Xbt, float* __restrict__ sq) {
  int tid  = threadIdx.x;
  int row  = blockIdx.x * 4 + (tid >> 6);  // one wave per row
  int lane = tid & 63;
  const float* rowp = (row < BS) ? (src + (size_t)row * D_DIM)
                                 : (tgt + (size_t)(row - BS) * D_DIM);
  float4 v = reinterpret_cast<const float4*>(rowp)[lane];   // cols k..k+3, k = lane*4
  ushort4 b;
  b.x = f2bf(v.x); b.y = f2bf(v.y); b.z = f2bf(v.z); b.w = f2bf(v.w);
  int k = lane * 4;
  size_t off = ((size_t)(row >> 4)) * 4096 + (size_t)(k >> 3) * 128
             + (size_t)((row & 15) * 8) + (k & 7);          // k..k+3 stay contiguous
  *reinterpret_cast<ushort4*>(Xbt + off) = b;
  float fx = bf2f(b.x), fy = bf2f(b.y), fz = bf2f(b.z), fw = bf2f(b.w);
  float s = fx * fx + fy * fy + fz * fz + fw * fw;
  #pragma unroll
  for (int o = 32; o; o >>= 1) s += __shfl_down(s, o, 64);
  if (lane == 0) sq[row] = s;
}

// ---------------- column sums + (last block) bandwidth coefficient ----------------
__global__ void colsum_kernel(const float* __restrict__ src, const float* __restrict__ tgt,
                              double* __restrict__ colsum, const float* __restrict__ sq,
                              int* __restrict__ cnt, float* __restrict__ coef) {
  int d  = threadIdx.x;           // 256 threads = one per column
  int r0 = blockIdx.x * 32;       // 256 blocks * 32 rows
  float s = 0.f;
  #pragma unroll
  for (int r = 0; r < 32; ++r) {
    int row = r0 + r;
    const float* rowp = (row < BS) ? (src + (size_t)row * D_DIM)
                                   : (tgt + (size_t)(row - BS) * D_DIM);
    s += rowp[d];
  }
  atomicAdd(&colsum[d], (double)s);
  __threadfence();
  __shared__ int ticket;
  if (d == 0) ticket = atomicAdd(cnt, 1);
  __syncthreads();
  if (ticket != 255) return;

  // last block: compute coef (colsum atomics globally visible; read atomically)
  int t = d, w = t >> 6, lane = t & 63;
  double s1 = 0.0;
  #pragma unroll
  for (int i = 0; i < 32; ++i) s1 += (double)sq[t + i * 256];
  double c  = atomicAdd(&colsum[t], 0.0);   // coherent cross-XCD read
  double s2 = c * c;
  #pragma unroll
  for (int o = 32; o; o >>= 1) { s1 += __shfl_down(s1, o, 64); s2 += __shfl_down(s2, o, 64); }
  __shared__ double rs[4], rs2[4];
  if (lane == 0) { rs[w] = s1; rs2[w] = s2; }
  __syncthreads();
  if (t == 0) {
    double S1 = rs[0] + rs[1] + rs[2] + rs[3];
    double S2 = rs2[0] + rs2[1] + rs2[2] + rs2[3];
    double S  = 2.0 * (double)N_TOT * S1 - 2.0 * S2;   // sum of all pairwise sq dists
    double bw = (S / ((double)N_TOT * (double)N_TOT - (double)N_TOT)) / 4.0;
    // u = exp(-l2/(16 bw)) = exp2(l2 * coef); kernels = u+u^2+u^4+u^8+u^16
    *coef = (float)(-1.4426950408889634 / (16.0 * bw));
  }
}

// ---------------- fused gram + RBF epilogue + (last block) finalize ----------------
// 8320 one-wave blocks; each computes one 64x64 quadrant of a 128x128 tile.
__launch_bounds__(64, 3)
__global__ void gram_kernel(const unsigned short* __restrict__ Xbt, const float* __restrict__ sq,
                            const float* __restrict__ coefp, double* __restrict__ partial,
                            int* __restrict__ cnt, float* __restrict__ out) {
  int lane = threadIdx.x;
  const int lo = lane & 15, hi = lane >> 4;

  // XCD-contiguous swizzle (8320 = 8 * 1040): XCD c gets ids [c*1040, (c+1)*1040)
  int orig = (int)blockIdx.x;
  int id   = (orig & 7) * (NQUAD / 8) + (orig >> 3);

  int tile = id >> 2, quad = id & 3;
  const int wr = quad >> 1, wc = quad & 1;

  // macro-major decode of tile -> (bi, bj), bi <= bj. Macro = 8x8 tiles;
  // off-diag macro: 64 tiles, diag macro: 36 (upper-tri).
  int bi = 0, bj = 0;
  {
    int rem = tile, Mi = 0, Mj = 0;
    for (Mi = 0; Mi < 8; ++Mi) {
      bool found = false;
      for (Mj = Mi; Mj < 8; ++Mj) {
        int cntm = (Mi == Mj) ? 36 : 64;
        if (rem < cntm) { found = true; break; }
        rem -= cntm;
      }
      if (found) break;
    }
    int ti, tj;
    if (Mi == Mj) {                    // upper-tri decode within 8x8
      ti = 0;
      while (rem >= 8 - ti) { rem -= 8 - ti; ++ti; }
      tj = ti + rem;
    } else {
      ti = rem >> 3; tj = rem & 7;
    }
    bi = Mi * 8 + ti; bj = Mj * 8 + tj;
  }

  float factor = ((bi < 32) == (bj < 32)) ? 1.f : -1.f;  // sign of the mean term
  if (bi != bj) factor *= 2.f;                            // symmetry weight

  // hoist epilogue scalars above the K-loop
  float coef = *coefp;
  float sqj[4], sqi[4][4];
  #pragma unroll
  for (int n = 0; n < 4; ++n) sqj[n] = sq[bj * 128 + wc * 64 + n * 16 + lo];
  #pragma unroll
  for (int m = 0; m < 4; ++m)
    #pragma unroll
    for (int r = 0; r < 4; ++r) sqi[m][r] = sq[bi * 128 + wr * 64 + m * 16 + hi * 4 + r];

  // fragment base (coalesced layout): rowgroup*8192 + (kc*4+hi)*256 + lo*16 bytes
  const char* pA = (const char*)Xbt + (size_t)(bi * 8 + wr * 4) * 8192 + (hi * 256 + lo * 16);
  const char* pB = (const char*)Xbt + (size_t)(bj * 8 + wc * 4) * 8192 + (hi * 256 + lo * 16);
  // m-step = +8192 B (one 16-row group); kc-step = +1024 B

  f32x4 acc[4][4];
  #pragma unroll
  for (int m = 0; m < 4; ++m)
    #pragma unroll
    for (int n = 0; n < 4; ++n) acc[m][n] = (f32x4){0.f, 0.f, 0.f, 0.f};

  bf16x8 a0[4], b0[4], a1[4], b1[4];

  auto load = [&](bf16x8* a, bf16x8* b, int kc) {
    #pragma unroll
    for (int m = 0; m < 4; ++m) a[m] = *(const bf16x8*)(pA + m * 8192 + kc * 1024);
    #pragma unroll
    for (int n = 0; n < 4; ++n) b[n] = *(const bf16x8*)(pB + n * 8192 + kc * 1024);
  };
  auto mm = [&](bf16x8* a, bf16x8* b) {
    #pragma unroll
    for (int m = 0; m < 4; ++m)
      #pragma unroll
      for (int n = 0; n < 4; ++n)
        acc[m][n] = __builtin_amdgcn_mfma_f32_16x16x32_bf16(a[m], b[n], acc[m][n], 0, 0, 0);
  };

  load(a0, b0, 0);
  #pragma unroll
  for (int kc = 0; kc < 8; ++kc) {       // D=256 -> 8 chunks of K=32
    if (kc & 1) {
      if (kc < 7) load(a0, b0, kc + 1);
      mm(a1, b1);
    } else {
      if (kc < 7) load(a1, b1, kc + 1);
      mm(a0, b0);
    }
  }

  // epilogue: d2 = max(sq_i + sq_j - 2g, 0); kernels = u+u^2+u^4+u^8+u^16, u=exp2(d2*coef)
  float psum = 0.f;
  #pragma unroll
  for (int m = 0; m < 4; ++m) {
    #pragma unroll
    for (int n = 0; n < 4; ++n) {
      #pragma unroll
      for (int r = 0; r < 4; ++r) {
        float g  = acc[m][n][r];
        float d2 = fmaxf(fmaf(-2.f, g, sqi[m][r] + sqj[n]), 0.f);
        float u  = __builtin_amdgcn_exp2f(d2 * coef);
        float u2 = u * u, u4 = u2 * u2, u8 = u4 * u4, u16 = u8 * u8;
        psum += (u + u2) + (u4 + u8) + u16;
      }
    }
  }
  #pragma unroll
  for (int o = 32; o; o >>= 1) psum += __shfl_down(psum, o, 64);

  // per-block result -> one of 256 distinct slots (pipelined, no serial chain)
  if (lane == 0) atomicAdd(&partial[id & 255], (double)(psum * factor));
  __threadfence();
  int tk = 0;
  if (lane == 0) tk = atomicAdd(cnt, 1);
  tk = __shfl(tk, 0, 64);
  if (tk != NQUAD - 1) return;

  // last block: reduce the 256 slots and finalize
  double s = 0.0;
  #pragma unroll
  for (int j = 0; j < 4; ++j) s += atomicAdd(&partial[lane * 4 + j], 0.0);
  #pragma unroll
  for (int o = 32; o; o >>= 1) s += __shfl_down(s, o, 64);
  if (lane == 0) out[0] = (float)(s / ((double)BS * (double)BS));
}

extern "C" void kernel_launch(void* const* d_in, const int* in_sizes, int n_in,
                              void* d_out, int out_size, void* d_ws, size_t ws_size,
                              hipStream_t stream) {
  const float* src = (const float*)d_in[0];
  const float* tgt = (const float*)d_in[1];
  char* ws = (char*)d_ws;
  int*    cnt_cs  = (int*)(ws + 0);
  int*    cnt_gr  = (int*)(ws + 4);
  float*  coef    = (float*)(ws + 8);
  double* colsum  = (double*)(ws + 16);
  double* partial = (double*)(ws + 2080);
  float*  sq      = (float*)(ws + 8192);
  unsigned short* Xbt = (unsigned short*)(ws + 40960);
  float* out = (float*)d_out;

  (void)hipMemsetAsync(d_ws, 0, 8192, stream);  // zero tickets/colsum/partials
  prep_kernel<<<2048, 256, 0, stream>>>(src, tgt, Xbt, sq);
  colsum_kernel<<<256, 256, 0, stream>>>(src, tgt, colsum, sq, cnt_cs, coef);
  gram_kernel<<<NQUAD, 64, 0, stream>>>(Xbt, sq, coef, partial, cnt_gr, out);
}

// Round 7
// 61.630 us; speedup vs baseline: 5.1684x; 5.1684x over previous
//
#include <hip/hip_runtime.h>
#include <stdint.h>
#include <stddef.h>

// MMD loss, fused: gram = X·X^T (bf16 MFMA) + 5-kernel RBF epilogue + signed mean.
// N=8192 rows (4096 src + 4096 tgt), D=256.
//
// Round-7 structure: NO LDS staging; Xbt pre-transposed to MFMA fragment order
// (1KB/wave coalesced fragment loads). NEW vs rounds 4-6: ZERO device-scope
// serialization in the hot kernel. Evidence: R5->R6 duration scaled exactly
// with nblocks (75us@2080 -> 290us@8320, WRITE_SIZE = 64B x nblocks), i.e.
// the per-block {atomicAdd -> threadfence(L2 writeback) -> ticket RMW} tail
// was a ~36ns-per-block device-wide serial chain that hid the whole GEMM.
// Now: gram blocks write partials via PLAIN stores to distinct slots; the
// bandwidth coef and the final reduction are separate tiny kernels (stream
// order makes prior-kernel writes visible; no fences/tickets anywhere).
//
// Fragment layout: elem(r,k) at (r>>4)*4096 + (k>>3)*128 + (r&15)*8 + (k&7)
// -> lane(lo,hi) fragment base byte = rowgroup*8192 + (kc*4+hi)*256 + lo*16.
//
// ws layout:
//   [0]     double colsum[256]     -> [0, 2048)
//   [2048]  float  coef
//   [4096]  double partial[2080]   -> [4096, 20736)
//   [24576] float  sq[8192]        -> [24576, 57344)
//   [57344] ushort Xbt[8192*256]   (bf16, fragment-transposed, 4 MB)

#define N_TOT 8192
#define D_DIM 256
#define BS    4096
#define NB    64      // 128-row tiles per dim
#define NTILE 2080    // upper-tri 128x128 tiles (% 8 == 0)

typedef float  f32x4  __attribute__((ext_vector_type(4)));
typedef short  bf16x8 __attribute__((ext_vector_type(8)));

__device__ __forceinline__ unsigned short f2bf(float f) {
  unsigned u = __float_as_uint(f);
  u += 0x7fffu + ((u >> 16) & 1u);   // RNE; inputs are finite
  return (unsigned short)(u >> 16);
}
__device__ __forceinline__ float bf2f(unsigned short s) {
  return __uint_as_float(((unsigned)s) << 16);
}

// ---------------- prep: f32 -> bf16 fragment-transposed copy + row sq-norms ----------------
__global__ void prep_kernel(const float* __restrict__ src, const float* __restrict__ tgt,
                            unsigned short* __restrict__ Xbt, float* __restrict__ sq) {
  int tid  = threadIdx.x;
  int row  = blockIdx.x * 4 + (tid >> 6);  // one wave per row
  int lane = tid & 63;
  const float* rowp = (row < BS) ? (src + (size_t)row * D_DIM)
                                 : (tgt + (size_t)(row - BS) * D_DIM);
  float4 v = reinterpret_cast<const float4*>(rowp)[lane];   // cols k..k+3, k = lane*4
  ushort4 b;
  b.x = f2bf(v.x); b.y = f2bf(v.y); b.z = f2bf(v.z); b.w = f2bf(v.w);
  int k = lane * 4;
  size_t off = ((size_t)(row >> 4)) * 4096 + (size_t)(k >> 3) * 128
             + (size_t)((row & 15) * 8) + (k & 7);          // k..k+3 stay contiguous
  *reinterpret_cast<ushort4*>(Xbt + off) = b;
  float fx = bf2f(b.x), fy = bf2f(b.y), fz = bf2f(b.z), fw = bf2f(b.w);
  float s = fx * fx + fy * fy + fz * fz + fw * fw;
  #pragma unroll
  for (int o = 32; o; o >>= 1) s += __shfl_down(s, o, 64);
  if (lane == 0) sq[row] = s;
}

// ---------------- column sums (256 distinct-address atomics, no fence/ticket) ----------------
__global__ void colsum_kernel(const float* __restrict__ src, const float* __restrict__ tgt,
                              double* __restrict__ colsum) {
  int d  = threadIdx.x;           // 256 threads = one per column
  int r0 = blockIdx.x * 32;       // 256 blocks * 32 rows
  float s = 0.f;
  #pragma unroll
  for (int r = 0; r < 32; ++r) {
    int row = r0 + r;
    const float* rowp = (row < BS) ? (src + (size_t)row * D_DIM)
                                   : (tgt + (size_t)(row - BS) * D_DIM);
    s += rowp[d];
  }
  atomicAdd(&colsum[d], (double)s);
}

// ---------------- bandwidth coefficient (separate kernel; stream order = visibility) ----------
__global__ void bw_kernel(const float* __restrict__ sq, const double* __restrict__ colsum,
                          float* __restrict__ coef) {
  int t = threadIdx.x, w = t >> 6, lane = t & 63;
  double s1 = 0.0;
  #pragma unroll
  for (int i = 0; i < 32; ++i) s1 += (double)sq[t + i * 256];
  double c  = colsum[t];
  double s2 = c * c;
  #pragma unroll
  for (int o = 32; o; o >>= 1) { s1 += __shfl_down(s1, o, 64); s2 += __shfl_down(s2, o, 64); }
  __shared__ double rs[4], rs2[4];
  if (lane == 0) { rs[w] = s1; rs2[w] = s2; }
  __syncthreads();
  if (t == 0) {
    double S1 = rs[0] + rs[1] + rs[2] + rs[3];
    double S2 = rs2[0] + rs2[1] + rs2[2] + rs2[3];
    double S  = 2.0 * (double)N_TOT * S1 - 2.0 * S2;   // sum of all pairwise sq dists
    double bw = (S / ((double)N_TOT * (double)N_TOT - (double)N_TOT)) / 4.0;
    // u = exp(-l2/(16 bw)) = exp2(l2 * coef); kernels = u+u^2+u^4+u^8+u^16
    *coef = (float)(-1.4426950408889634 / (16.0 * bw));
  }
}

// ---------------- fused gram + RBF epilogue; plain-store partial per block ----------------
// 2080 blocks, 4 waves; each wave one 64x64 quadrant of a 128x128 tile.
__launch_bounds__(256, 3)
__global__ void gram_kernel(const unsigned short* __restrict__ Xbt, const float* __restrict__ sq,
                            const float* __restrict__ coefp, double* __restrict__ partial) {
  int tid = threadIdx.x;
  int w = tid >> 6, lane = tid & 63;
  const int lo = lane & 15, hi = lane >> 4;
  const int wr = w >> 1, wc = w & 1;

  // XCD-contiguous swizzle (2080 % 8 == 0): XCD c gets ids [c*260, (c+1)*260)
  int orig = (int)blockIdx.x;
  int id   = (orig & 7) * (NTILE / 8) + (orig >> 3);

  // macro-major decode of tile -> (bi, bj), bi <= bj. Macro = 8x8 tiles;
  // off-diag macro: 64 tiles, diag macro: 36 (upper-tri).
  int bi = 0, bj = 0;
  {
    int rem = id, Mi = 0, Mj = 0;
    for (Mi = 0; Mi < 8; ++Mi) {
      bool found = false;
      for (Mj = Mi; Mj < 8; ++Mj) {
        int cntm = (Mi == Mj) ? 36 : 64;
        if (rem < cntm) { found = true; break; }
        rem -= cntm;
      }
      if (found) break;
    }
    int ti, tj;
    if (Mi == Mj) {                    // upper-tri decode within 8x8
      ti = 0;
      while (rem >= 8 - ti) { rem -= 8 - ti; ++ti; }
      tj = ti + rem;
    } else {
      ti = rem >> 3; tj = rem & 7;
    }
    bi = Mi * 8 + ti; bj = Mj * 8 + tj;
  }

  float factor = ((bi < 32) == (bj < 32)) ? 1.f : -1.f;  // sign of the mean term
  if (bi != bj) factor *= 2.f;                            // symmetry weight

  // hoist epilogue scalars above the K-loop
  float coef = *coefp;
  float sqj[4], sqi[4][4];
  #pragma unroll
  for (int n = 0; n < 4; ++n) sqj[n] = sq[bj * 128 + wc * 64 + n * 16 + lo];
  #pragma unroll
  for (int m = 0; m < 4; ++m)
    #pragma unroll
    for (int r = 0; r < 4; ++r) sqi[m][r] = sq[bi * 128 + wr * 64 + m * 16 + hi * 4 + r];

  // fragment base (coalesced layout): rowgroup*8192 + (kc*4+hi)*256 + lo*16 bytes
  const char* pA = (const char*)Xbt + (size_t)(bi * 8 + wr * 4) * 8192 + (hi * 256 + lo * 16);
  const char* pB = (const char*)Xbt + (size_t)(bj * 8 + wc * 4) * 8192 + (hi * 256 + lo * 16);
  // m-step = +8192 B (one 16-row group); kc-step = +1024 B

  f32x4 acc[4][4];
  #pragma unroll
  for (int m = 0; m < 4; ++m)
    #pragma unroll
    for (int n = 0; n < 4; ++n) acc[m][n] = (f32x4){0.f, 0.f, 0.f, 0.f};

  bf16x8 a0[4], b0[4], a1[4], b1[4];

  auto load = [&](bf16x8* a, bf16x8* b, int kc) {
    #pragma unroll
    for (int m = 0; m < 4; ++m) a[m] = *(const bf16x8*)(pA + m * 8192 + kc * 1024);
    #pragma unroll
    for (int n = 0; n < 4; ++n) b[n] = *(const bf16x8*)(pB + n * 8192 + kc * 1024);
  };
  auto mm = [&](bf16x8* a, bf16x8* b) {
    #pragma unroll
    for (int m = 0; m < 4; ++m)
      #pragma unroll
      for (int n = 0; n < 4; ++n)
        acc[m][n] = __builtin_amdgcn_mfma_f32_16x16x32_bf16(a[m], b[n], acc[m][n], 0, 0, 0);
  };

  load(a0, b0, 0);
  #pragma unroll
  for (int kc = 0; kc < 8; ++kc) {       // D=256 -> 8 chunks of K=32
    if (kc & 1) {
      if (kc < 7) load(a0, b0, kc + 1);
      mm(a1, b1);
    } else {
      if (kc < 7) load(a1, b1, kc + 1);
      mm(a0, b0);
    }
  }

  // epilogue: d2 = max(sq_i + sq_j - 2g, 0); kernels = u+u^2+u^4+u^8+u^16, u=exp2(d2*coef)
  float psum = 0.f;
  #pragma unroll
  for (int m = 0; m < 4; ++m) {
    #pragma unroll
    for (int n = 0; n < 4; ++n) {
      #pragma unroll
      for (int r = 0; r < 4; ++r) {
        float g  = acc[m][n][r];
        float d2 = fmaxf(fmaf(-2.f, g, sqi[m][r] + sqj[n]), 0.f);
        float u  = __builtin_amdgcn_exp2f(d2 * coef);
        float u2 = u * u, u4 = u2 * u2, u8 = u4 * u4, u16 = u8 * u8;
        psum += (u + u2) + (u4 + u8) + u16;
      }
    }
  }
  #pragma unroll
  for (int o = 32; o; o >>= 1) psum += __shfl_down(psum, o, 64);
  __shared__ float wred[4];
  if (lane == 0) wred[w] = psum;
  __syncthreads();
  if (tid == 0)
    partial[id] = (double)((wred[0] + wred[1] + wred[2] + wred[3]) * factor);  // plain store
}

// ---------------- final reduction (1 block; stream order = visibility) ----------------
__global__ void reduce_kernel(const double* __restrict__ partial, float* __restrict__ out) {
  int t = threadIdx.x, w = t >> 6, lane = t & 63;
  double s = 0.0;
  for (int i = t; i < NTILE; i += 256) s += partial[i];
  #pragma unroll
  for (int o = 32; o; o >>= 1) s += __shfl_down(s, o, 64);
  __shared__ double rs[4];
  if (lane == 0) rs[w] = s;
  __syncthreads();
  if (t == 0)
    out[0] = (float)((rs[0] + rs[1] + rs[2] + rs[3]) / ((double)BS * (double)BS));
}

extern "C" void kernel_launch(void* const* d_in, const int* in_sizes, int n_in,
                              void* d_out, int out_size, void* d_ws, size_t ws_size,
                              hipStream_t stream) {
  const float* src = (const float*)d_in[0];
  const float* tgt = (const float*)d_in[1];
  char* ws = (char*)d_ws;
  double* colsum  = (double*)(ws + 0);
  float*  coef    = (float*)(ws + 2048);
  double* partial = (double*)(ws + 4096);
  float*  sq      = (float*)(ws + 24576);
  unsigned short* Xbt = (unsigned short*)(ws + 57344);
  float* out = (float*)d_out;

  (void)hipMemsetAsync(ws, 0, 2048, stream);  // zero colsum only
  prep_kernel<<<2048, 256, 0, stream>>>(src, tgt, Xbt, sq);
  colsum_kernel<<<256, 256, 0, stream>>>(src, tgt, colsum);
  bw_kernel<<<1, 256, 0, stream>>>(sq, colsum, coef);
  gram_kernel<<<NTILE, 256, 0, stream>>>(Xbt, sq, coef, partial);
  reduce_kernel<<<1, 256, 0, stream>>>(partial, out);
}

// Round 8
// 60.011 us; speedup vs baseline: 5.3079x; 1.0270x over previous
//
#include <hip/hip_runtime.h>
#include <stdint.h>
#include <stddef.h>

// MMD loss, fused: gram = X·X^T (bf16 MFMA) + 5-kernel RBF epilogue + signed mean.
// N=8192 rows (4096 src + 4096 tgt), D=256.
//
// Round-8 structure (evidence-driven deltas from R7's 61.6us):
//  (a) colsum fused into prep (one 8MB pass, LDS-reduced block partials,
//      plain stores) and the ws memset is GONE (no atomics -> nothing needs
//      pre-zeroing). 6 dispatches -> 4.
//  (b) gram register diet: B fragments single-buffered (JIT per K-chunk),
//      epilogue sq loads moved after the K-loop, __launch_bounds__(256,4).
//      R7 evidence: occupancy ~22% (136 unified regs -> 2-3 waves/SIMD) with
//      ~300cyc L2 fragment latency and 1-deep prefetch = latency-bound.
//  (c) still ZERO device-scope serialization in gram (R6 lesson: the
//      fence/ticket tail serialized ~36ns/block device-wide).
//
// Fragment layout: elem(r,k) at (r>>4)*4096 + (k>>3)*128 + (r&15)*8 + (k&7)
// -> lane(lo,hi) fragment base byte = rowgroup*8192 + (kc*4+hi)*256 + lo*16
//    (contiguous 1KB per wave per fragment load).
//
// ws layout:
//   [0]      float  coef            (-log2(e)/(16*bandwidth))
//   [64]     double partial[2080]   -> [64, 16704)
//   [16704]  float  csp[256*256]    (per-block column-sum partials) -> 278848
//   [278848] float  sq[8192]        -> [278848, 311616)
//   [311616] ushort Xbt[8192*256]   (bf16, fragment-transposed, 4MB)

#define N_TOT 8192
#define D_DIM 256
#define BS    4096
#define NB    64      // 128-row tiles per dim
#define NTILE 2080    // upper-tri 128x128 tiles (% 8 == 0)

typedef float  f32x4  __attribute__((ext_vector_type(4)));
typedef short  bf16x8 __attribute__((ext_vector_type(8)));

__device__ __forceinline__ unsigned short f2bf(float f) {
  unsigned u = __float_as_uint(f);
  u += 0x7fffu + ((u >> 16) & 1u);   // RNE; inputs are finite
  return (unsigned short)(u >> 16);
}
__device__ __forceinline__ float bf2f(unsigned short s) {
  return __uint_as_float(((unsigned)s) << 16);
}

// ---- prep: f32 -> bf16 fragment-transposed copy + row sq-norms + column partials ----
// 256 blocks x 512 threads; 32 rows/block, 4 rows/wave.
__global__ void prep_kernel(const float* __restrict__ src, const float* __restrict__ tgt,
                            unsigned short* __restrict__ Xbt, float* __restrict__ sq,
                            float* __restrict__ csp) {
  int tid  = threadIdx.x;
  int w    = tid >> 6, lane = tid & 63;
  int blk  = blockIdx.x;
  float4 cacc = {0.f, 0.f, 0.f, 0.f};

  #pragma unroll
  for (int r = 0; r < 4; ++r) {
    int row = blk * 32 + w * 4 + r;
    const float* rowp = (row < BS) ? (src + (size_t)row * D_DIM)
                                   : (tgt + (size_t)(row - BS) * D_DIM);
    float4 v = reinterpret_cast<const float4*>(rowp)[lane];   // cols k..k+3, k=lane*4
    cacc.x += v.x; cacc.y += v.y; cacc.z += v.z; cacc.w += v.w;
    ushort4 b;
    b.x = f2bf(v.x); b.y = f2bf(v.y); b.z = f2bf(v.z); b.w = f2bf(v.w);
    int k = lane * 4;
    size_t off = ((size_t)(row >> 4)) * 4096 + (size_t)(k >> 3) * 128
               + (size_t)((row & 15) * 8) + (k & 7);
    *reinterpret_cast<ushort4*>(Xbt + off) = b;
    float fx = bf2f(b.x), fy = bf2f(b.y), fz = bf2f(b.z), fw = bf2f(b.w);
    float s = fx * fx + fy * fy + fz * fz + fw * fw;
    #pragma unroll
    for (int o = 32; o; o >>= 1) s += __shfl_down(s, o, 64);
    if (lane == 0) sq[row] = s;
  }

  __shared__ float cs[8][256];
  reinterpret_cast<float4*>(&cs[w][0])[lane] = cacc;
  __syncthreads();
  if (tid < 256) {
    float s = 0.f;
    #pragma unroll
    for (int ww = 0; ww < 8; ++ww) s += cs[ww][tid];
    csp[blk * 256 + tid] = s;   // plain store, distinct address
  }
}

// ---- bandwidth coefficient (1 block; stream order = visibility) ----
__global__ void bw_kernel(const float* __restrict__ sq, const float* __restrict__ csp,
                          float* __restrict__ coef) {
  int t = threadIdx.x, w = t >> 6, lane = t & 63;
  double s1 = 0.0;
  #pragma unroll
  for (int i = 0; i < 32; ++i) s1 += (double)sq[t + i * 256];
  double c = 0.0;
  for (int b = 0; b < 256; ++b) c += (double)csp[b * 256 + t];   // coalesced
  double s2 = c * c;
  #pragma unroll
  for (int o = 32; o; o >>= 1) { s1 += __shfl_down(s1, o, 64); s2 += __shfl_down(s2, o, 64); }
  __shared__ double rs[4], rs2[4];
  if (lane == 0) { rs[w] = s1; rs2[w] = s2; }
  __syncthreads();
  if (t == 0) {
    double S1 = rs[0] + rs[1] + rs[2] + rs[3];
    double S2 = rs2[0] + rs2[1] + rs2[2] + rs2[3];
    double S  = 2.0 * (double)N_TOT * S1 - 2.0 * S2;   // sum of all pairwise sq dists
    double bw = (S / ((double)N_TOT * (double)N_TOT - (double)N_TOT)) / 4.0;
    *coef = (float)(-1.4426950408889634 / (16.0 * bw));
  }
}

// ---- fused gram + RBF epilogue; plain-store partial per block ----
// 2080 blocks, 4 waves; each wave one 64x64 quadrant of a 128x128 tile.
__launch_bounds__(256, 4)
__global__ void gram_kernel(const unsigned short* __restrict__ Xbt, const float* __restrict__ sq,
                            const float* __restrict__ coefp, double* __restrict__ partial) {
  int tid = threadIdx.x;
  int w = tid >> 6, lane = tid & 63;
  const int lo = lane & 15, hi = lane >> 4;
  const int wr = w >> 1, wc = w & 1;

  // XCD-contiguous swizzle (2080 % 8 == 0)
  int orig = (int)blockIdx.x;
  int id   = (orig & 7) * (NTILE / 8) + (orig >> 3);

  // macro-major decode of tile -> (bi, bj), bi <= bj (macro = 8x8 tiles)
  int bi = 0, bj = 0;
  {
    int rem = id, Mi = 0, Mj = 0;
    for (Mi = 0; Mi < 8; ++Mi) {
      bool found = false;
      for (Mj = Mi; Mj < 8; ++Mj) {
        int cntm = (Mi == Mj) ? 36 : 64;
        if (rem < cntm) { found = true; break; }
        rem -= cntm;
      }
      if (found) break;
    }
    int ti, tj;
    if (Mi == Mj) {
      ti = 0;
      while (rem >= 8 - ti) { rem -= 8 - ti; ++ti; }
      tj = ti + rem;
    } else {
      ti = rem >> 3; tj = rem & 7;
    }
    bi = Mi * 8 + ti; bj = Mj * 8 + tj;
  }

  float factor = ((bi < 32) == (bj < 32)) ? 1.f : -1.f;
  if (bi != bj) factor *= 2.f;

  // fragment base (coalesced layout): rowgroup*8192 + (kc*4+hi)*256 + lo*16 bytes
  const char* pA = (const char*)Xbt + (size_t)(bi * 8 + wr * 4) * 8192 + (hi * 256 + lo * 16);
  const char* pB = (const char*)Xbt + (size_t)(bj * 8 + wc * 4) * 8192 + (hi * 256 + lo * 16);

  f32x4 acc[4][4];
  #pragma unroll
  for (int m = 0; m < 4; ++m)
    #pragma unroll
    for (int n = 0; n < 4; ++n) acc[m][n] = (f32x4){0.f, 0.f, 0.f, 0.f};

  bf16x8 a0[4], a1[4], b[4];   // A double-buffered, B JIT (register diet for 4 waves/SIMD)

  auto loadA = [&](bf16x8* a, int kc) {
    #pragma unroll
    for (int m = 0; m < 4; ++m) a[m] = *(const bf16x8*)(pA + m * 8192 + kc * 1024);
  };
  auto loadB = [&](int kc) {
    #pragma unroll
    for (int n = 0; n < 4; ++n) b[n] = *(const bf16x8*)(pB + n * 8192 + kc * 1024);
  };
  auto mm = [&](bf16x8* a) {
    #pragma unroll
    for (int m = 0; m < 4; ++m)
      #pragma unroll
      for (int n = 0; n < 4; ++n)
        acc[m][n] = __builtin_amdgcn_mfma_f32_16x16x32_bf16(a[m], b[n], acc[m][n], 0, 0, 0);
  };

  loadA(a0, 0);
  #pragma unroll
  for (int kc = 0; kc < 8; ++kc) {       // D=256 -> 8 chunks of K=32
    loadB(kc);                           // issue B first (earliest latency start)
    if (kc & 1) {
      if (kc < 7) loadA(a0, kc + 1);
      mm(a1);
    } else {
      if (kc < 7) loadA(a1, kc + 1);
      mm(a0);
    }
  }

  // epilogue (sq loads AFTER the K-loop to keep K-loop register pressure low)
  float coef = *coefp;
  float sqj[4], sqi[4][4];
  #pragma unroll
  for (int n = 0; n < 4; ++n) sqj[n] = sq[bj * 128 + wc * 64 + n * 16 + lo];
  #pragma unroll
  for (int m = 0; m < 4; ++m)
    #pragma unroll
    for (int r = 0; r < 4; ++r) sqi[m][r] = sq[bi * 128 + wr * 64 + m * 16 + hi * 4 + r];

  float psum = 0.f;
  #pragma unroll
  for (int m = 0; m < 4; ++m) {
    #pragma unroll
    for (int n = 0; n < 4; ++n) {
      #pragma unroll
      for (int r = 0; r < 4; ++r) {
        float g  = acc[m][n][r];
        float d2 = fmaxf(fmaf(-2.f, g, sqi[m][r] + sqj[n]), 0.f);
        float u  = __builtin_amdgcn_exp2f(d2 * coef);
        float u2 = u * u, u4 = u2 * u2, u8 = u4 * u4, u16 = u8 * u8;
        psum += (u + u2) + (u4 + u8) + u16;
      }
    }
  }
  #pragma unroll
  for (int o = 32; o; o >>= 1) psum += __shfl_down(psum, o, 64);
  __shared__ float wred[4];
  if (lane == 0) wred[w] = psum;
  __syncthreads();
  if (tid == 0)
    partial[id] = (double)((wred[0] + wred[1] + wred[2] + wred[3]) * factor);  // plain store
}

// ---- final reduction (1 block; stream order = visibility) ----
__global__ void reduce_kernel(const double* __restrict__ partial, float* __restrict__ out) {
  int t = threadIdx.x, w = t >> 6, lane = t & 63;
  double s = 0.0;
  for (int i = t; i < NTILE; i += 256) s += partial[i];
  #pragma unroll
  for (int o = 32; o; o >>= 1) s += __shfl_down(s, o, 64);
  __shared__ double rs[4];
  if (lane == 0) rs[w] = s;
  __syncthreads();
  if (t == 0)
    out[0] = (float)((rs[0] + rs[1] + rs[2] + rs[3]) / ((double)BS * (double)BS));
}

extern "C" void kernel_launch(void* const* d_in, const int* in_sizes, int n_in,
                              void* d_out, int out_size, void* d_ws, size_t ws_size,
                              hipStream_t stream) {
  const float* src = (const float*)d_in[0];
  const float* tgt = (const float*)d_in[1];
  char* ws = (char*)d_ws;
  float*  coef    = (float*)(ws + 0);
  double* partial = (double*)(ws + 64);
  float*  csp     = (float*)(ws + 16704);
  float*  sq      = (float*)(ws + 278848);
  unsigned short* Xbt = (unsigned short*)(ws + 311616);
  float* out = (float*)d_out;

  prep_kernel<<<256, 512, 0, stream>>>(src, tgt, Xbt, sq, csp);
  bw_kernel<<<1, 256, 0, stream>>>(sq, csp, coef);
  gram_kernel<<<NTILE, 256, 0, stream>>>(Xbt, sq, coef, partial);
  reduce_kernel<<<1, 256, 0, stream>>>(partial, out);
}